// Round 1
// baseline (828.570 us; speedup 1.0000x reference)
//
#include <hip/hip_runtime.h>

#define G 128
#define N 32
#define H 128
#define L 6

// ---------------------------------------------------------------------------
// E1: P0 = emb_x @ W0 + b0, P1 = emb_x @ W1 + b1   (emb_x has only 32 rows,
// so x@W collapses to a 32x128 GEMM + later gather). grid=2 (block 0 -> P0).
// ---------------------------------------------------------------------------
__global__ __launch_bounds__(256) void k_emb_mm(
    const float* __restrict__ emb_x,
    const float* __restrict__ W0, const float* __restrict__ b0, float* __restrict__ P0,
    const float* __restrict__ W1, const float* __restrict__ b1, float* __restrict__ P1) {
  const float* W = blockIdx.x ? W1 : W0;
  const float* b = blockIdx.x ? b1 : b0;
  float*       P = blockIdx.x ? P1 : P0;
  __shared__ float embs_t[128 * 32];   // [k][i]
  int tid = threadIdx.x;
  {
    int i = tid & 31, k0 = (tid >> 5) * 16;
    const float* src = emb_x + i * 128 + k0;
#pragma unroll
    for (int m = 0; m < 16; m++) embs_t[(k0 + m) * 32 + i] = src[m];
  }
  __syncthreads();
  int i  = tid >> 3;           // 0..31
  int h0 = (tid & 7) * 16;     // 0..112
  float acc[16];
#pragma unroll
  for (int hh = 0; hh < 16; hh++) acc[hh] = b[h0 + hh];
  for (int k = 0; k < 128; k++) {
    float a = embs_t[k * 32 + i];
    const float4* wr = (const float4*)(W + k * 128 + h0);
    float4 w0 = wr[0], w1 = wr[1], w2 = wr[2], w3 = wr[3];
    acc[0]  += a * w0.x; acc[1]  += a * w0.y; acc[2]  += a * w0.z; acc[3]  += a * w0.w;
    acc[4]  += a * w1.x; acc[5]  += a * w1.y; acc[6]  += a * w1.z; acc[7]  += a * w1.w;
    acc[8]  += a * w2.x; acc[9]  += a * w2.y; acc[10] += a * w2.z; acc[11] += a * w2.w;
    acc[12] += a * w3.x; acc[13] += a * w3.y; acc[14] += a * w3.z; acc[15] += a * w3.w;
  }
  float4* dst = (float4*)(P + i * 128 + h0);
  dst[0] = make_float4(acc[0], acc[1], acc[2], acc[3]);
  dst[1] = make_float4(acc[4], acc[5], acc[6], acc[7]);
  dst[2] = make_float4(acc[8], acc[9], acc[10], acc[11]);
  dst[3] = make_float4(acc[12], acc[13], acc[14], acc[15]);
}

// ---------------------------------------------------------------------------
// E2: build X in h-planar layout Xp[g][h][i*32+j] = x0[g,i,h]*x1[g,j,h]*etf[tf,h]
// one WG per graph. x0/x1 gathered from P0/P1 via x_idx; all LDS-transposed.
// ---------------------------------------------------------------------------
__global__ __launch_bounds__(256) void k_buildX(
    const int* __restrict__ x_idx, const int* __restrict__ tf_idx,
    const float* __restrict__ P0, const float* __restrict__ P1,
    const float* __restrict__ emb_tf, float* __restrict__ Xp) {
  int g = blockIdx.x, tid = threadIdx.x;
  __shared__ float x0t[128 * 32];   // [h][i]
  __shared__ float x1t[128 * 32];   // [h][j]
  __shared__ float etf[128 * 16];   // [h][t]
  __shared__ int   tfs[1024];
  {
    int i = tid & 31, h0 = (tid >> 5) * 16;
    int r = x_idx[g * 32 + i];
    const float* s0 = P0 + r * 128 + h0;
    const float* s1 = P1 + r * 128 + h0;
#pragma unroll
    for (int m = 0; m < 16; m++) {
      x0t[(h0 + m) * 32 + i] = s0[m];
      x1t[(h0 + m) * 32 + i] = s1[m];
    }
  }
  {
    int t = tid & 15, h0 = (tid >> 4) * 8;
    const float* s = emb_tf + t * 128 + h0;
#pragma unroll
    for (int m = 0; m < 8; m++) etf[(h0 + m) * 16 + t] = s[m];
  }
  ((int4*)tfs)[tid] = ((const int4*)(tf_idx + (size_t)g * 1024))[tid];
  __syncthreads();
  int i = tid >> 3, j0 = (tid & 7) * 4;
  int t0 = tfs[i * 32 + j0 + 0], t1 = tfs[i * 32 + j0 + 1];
  int t2 = tfs[i * 32 + j0 + 2], t3 = tfs[i * 32 + j0 + 3];
  float* outg = Xp + ((size_t)g << 17);
  for (int h = 0; h < 128; h++) {
    float a = x0t[h * 32 + i];
    const float* x1r = x1t + h * 32;
    const float* er  = etf + h * 16;
    float4 v;
    v.x = a * x1r[j0 + 0] * er[t0];
    v.y = a * x1r[j0 + 1] * er[t1];
    v.z = a * x1r[j0 + 2] * er[t2];
    v.w = a * x1r[j0 + 3] * er[t3];
    *(float4*)(outg + h * 1024 + tid * 4) = v;
  }
}

// ---------------------------------------------------------------------------
// K1: tXp = relu(LN(X @ Wc[l] + bc[l]))   in h-planar layout.
// GEMM over h' (K=128) per (g, 128-position block). 8x8 register tile/thread,
// split 4+4 at stride 64 so LDS b128 reads are 2-way-conflict-free.
// Two-pass LN over h (avoids E[x^2]-m^2 cancellation). grid = G*8.
// ---------------------------------------------------------------------------
__global__ __launch_bounds__(256) void k_conv_mlp(
    const float* __restrict__ Xp, const float* __restrict__ W,
    const float* __restrict__ bcl, const float* __restrict__ gcl,
    const float* __restrict__ ccl, float* __restrict__ tXp) {
  int g = blockIdx.x >> 3, pb = blockIdx.x & 7;
  int tid = threadIdx.x;
  __shared__ float Xs[16 * 132];
  __shared__ float Ws[16 * 132];
  __shared__ float red[128 * 17];
  __shared__ float mstat[128], rstat[128];
  int pt = tid & 15, ht = tid >> 4;
  int p0c = pt * 4, h0 = ht * 4;
  int hidxv[8];
  float bcv[8], gcv[8], ccv[8];
#pragma unroll
  for (int hi = 0; hi < 8; hi++) {
    int hcol = ht * 4 + (hi < 4 ? hi : 60 + hi);
    hidxv[hi] = hcol;
    bcv[hi] = bcl[hcol]; gcv[hi] = gcl[hcol]; ccv[hi] = ccl[hcol];
  }
  float acc[8][8];
#pragma unroll
  for (int pi = 0; pi < 8; pi++)
#pragma unroll
    for (int hi = 0; hi < 8; hi++) acc[pi][hi] = bcv[hi];

  const float* Xg = Xp + ((size_t)g << 17) + pb * 128;
  int lrow = tid >> 4, lc0 = (tid & 15) * 8;
  for (int kb = 0; kb < 8; kb++) {
    const float* xsrc = Xg + (size_t)(kb * 16 + lrow) * 1024 + lc0;
    float4 xa = *(const float4*)xsrc;
    float4 xb = *(const float4*)(xsrc + 4);
    const float* wsrc = W + (kb * 16 + lrow) * 128 + lc0;
    float4 wa = *(const float4*)wsrc;
    float4 wb = *(const float4*)(wsrc + 4);
    __syncthreads();
    *(float4*)&Xs[lrow * 132 + lc0]     = xa;
    *(float4*)&Xs[lrow * 132 + lc0 + 4] = xb;
    *(float4*)&Ws[lrow * 132 + lc0]     = wa;
    *(float4*)&Ws[lrow * 132 + lc0 + 4] = wb;
    __syncthreads();
#pragma unroll
    for (int kk = 0; kk < 16; kk++) {
      float4 a0 = *(const float4*)&Xs[kk * 132 + p0c];
      float4 a1 = *(const float4*)&Xs[kk * 132 + p0c + 64];
      float4 w0 = *(const float4*)&Ws[kk * 132 + h0];
      float4 w1 = *(const float4*)&Ws[kk * 132 + h0 + 64];
      float av[8] = {a0.x, a0.y, a0.z, a0.w, a1.x, a1.y, a1.z, a1.w};
      float wv[8] = {w0.x, w0.y, w0.z, w0.w, w1.x, w1.y, w1.z, w1.w};
#pragma unroll
      for (int pi = 0; pi < 8; pi++)
#pragma unroll
        for (int hi = 0; hi < 8; hi++) acc[pi][hi] += av[pi] * wv[hi];
    }
  }
  // ---- LN pass A: mean over h ----
  __syncthreads();
#pragma unroll
  for (int pi = 0; pi < 8; pi++) {
    int p = pt * 4 + (pi < 4 ? pi : 60 + pi);
    float s = 0.f;
#pragma unroll
    for (int hi = 0; hi < 8; hi++) s += acc[pi][hi];
    red[p * 17 + ht] = s;
  }
  __syncthreads();
  if (tid < 128) {
    float s = 0.f;
#pragma unroll
    for (int t = 0; t < 16; t++) s += red[tid * 17 + t];
    mstat[tid] = s * (1.f / 128.f);
  }
  __syncthreads();
  float mv[8];
#pragma unroll
  for (int pi = 0; pi < 8; pi++) mv[pi] = mstat[pt * 4 + (pi < 4 ? pi : 60 + pi)];
  // ---- LN pass B: variance ----
#pragma unroll
  for (int pi = 0; pi < 8; pi++) {
    int p = pt * 4 + (pi < 4 ? pi : 60 + pi);
    float q = 0.f;
#pragma unroll
    for (int hi = 0; hi < 8; hi++) { float d = acc[pi][hi] - mv[pi]; q += d * d; }
    red[p * 17 + ht] = q;
  }
  __syncthreads();
  if (tid < 128) {
    float s = 0.f;
#pragma unroll
    for (int t = 0; t < 16; t++) s += red[tid * 17 + t];
    rstat[tid] = rsqrtf(s * (1.f / 128.f) + 1e-5f);
  }
  __syncthreads();
  float rv[8];
#pragma unroll
  for (int pi = 0; pi < 8; pi++) rv[pi] = rstat[pt * 4 + (pi < 4 ? pi : 60 + pi)];
  // ---- normalize + relu + store ----
#pragma unroll
  for (int hi = 0; hi < 8; hi++) {
    int hcol = hidxv[hi];
    float* dst = tXp + (((size_t)(g * 128 + hcol)) << 10) + pb * 128 + pt * 4;
    float4 v0, v1;
    v0.x = fmaxf((acc[0][hi] - mv[0]) * rv[0] * gcv[hi] + ccv[hi], 0.f);
    v0.y = fmaxf((acc[1][hi] - mv[1]) * rv[1] * gcv[hi] + ccv[hi], 0.f);
    v0.z = fmaxf((acc[2][hi] - mv[2]) * rv[2] * gcv[hi] + ccv[hi], 0.f);
    v0.w = fmaxf((acc[3][hi] - mv[3]) * rv[3] * gcv[hi] + ccv[hi], 0.f);
    v1.x = fmaxf((acc[4][hi] - mv[4]) * rv[4] * gcv[hi] + ccv[hi], 0.f);
    v1.y = fmaxf((acc[5][hi] - mv[5]) * rv[5] * gcv[hi] + ccv[hi], 0.f);
    v1.z = fmaxf((acc[6][hi] - mv[6]) * rv[6] * gcv[hi] + ccv[hi], 0.f);
    v1.w = fmaxf((acc[7][hi] - mv[7]) * rv[7] * gcv[hi] + ccv[hi], 0.f);
    *(float4*)dst        = v0;
    *(float4*)(dst + 64) = v1;
  }
}

// ---------------------------------------------------------------------------
// K2: X[g,h,i,j] += sum_k tX[g,i,k,h] * (emb_ea[ea_idx[g,k,j],h]*adj[g,k,j]).
// One wave per (g,h) plane; 4 planes/WG. tX staged transposed [k][i] stride 36,
// A built on the fly in LDS [k][j] stride 36; 4x4 register tile per lane.
// grid = G*32.
// ---------------------------------------------------------------------------
__global__ __launch_bounds__(256) void k_conv_msg(
    const float* __restrict__ tXp, const int* __restrict__ ea_idx,
    const int* __restrict__ adj, const float* __restrict__ emb_ea,
    float* __restrict__ Xp) {
  int g  = blockIdx.x >> 5;
  int hb = (blockIdx.x & 31) * 4;
  int tid = threadIdx.x;
  int wave = tid >> 6, lane = tid & 63;
  int h = hb + wave;
  __shared__ int   eai[1024];
  __shared__ int   adjs[1024];
  __shared__ float eac[4][16];
  __shared__ __align__(16) float tXs[4][32 * 36];   // [k][i]
  __shared__ __align__(16) float As[4][32 * 36];    // [k][j]
  ((int4*)eai)[tid]  = ((const int4*)(ea_idx + (size_t)g * 1024))[tid];
  ((int4*)adjs)[tid] = ((const int4*)(adj + (size_t)g * 1024))[tid];
  if (lane < 16) eac[wave][lane] = emb_ea[lane * 128 + h];
  {
    const float4* src = (const float4*)(tXp + (((size_t)(g * 128 + h)) << 10) + lane * 16);
    float4 v[4];
#pragma unroll
    for (int m = 0; m < 4; m++) v[m] = src[m];
#pragma unroll
    for (int m = 0; m < 16; m++) {
      int p = lane * 16 + m;                     // p = i*32 + k
      tXs[wave][(p & 31) * 36 + (p >> 5)] = ((const float*)v)[m];
    }
  }
  __syncthreads();
#pragma unroll
  for (int m = 0; m < 16; m++) {
    int p = lane * 16 + m;                       // p = k*32 + j
    int e = eai[p];
    As[wave][(p >> 5) * 36 + (p & 31)] = adjs[p] ? eac[wave][e] : 0.f;
  }
  __syncthreads();
  int i0 = (lane >> 3) * 4, j0 = (lane & 7) * 4;
  float4 acc0 = {0, 0, 0, 0}, acc1 = {0, 0, 0, 0}, acc2 = {0, 0, 0, 0}, acc3 = {0, 0, 0, 0};
  const float* tw = tXs[wave];
  const float* aw = As[wave];
#pragma unroll
  for (int k = 0; k < 32; k++) {
    float4 a  = *(const float4*)&tw[k * 36 + i0];
    float4 bv = *(const float4*)&aw[k * 36 + j0];
    acc0.x += a.x * bv.x; acc0.y += a.x * bv.y; acc0.z += a.x * bv.z; acc0.w += a.x * bv.w;
    acc1.x += a.y * bv.x; acc1.y += a.y * bv.y; acc1.z += a.y * bv.z; acc1.w += a.y * bv.w;
    acc2.x += a.z * bv.x; acc2.y += a.z * bv.y; acc2.z += a.z * bv.z; acc2.w += a.z * bv.w;
    acc3.x += a.w * bv.x; acc3.y += a.w * bv.y; acc3.z += a.w * bv.z; acc3.w += a.w * bv.w;
  }
  float* xrow = Xp + (((size_t)(g * 128 + h)) << 10);
  float4* r0 = (float4*)(xrow + (i0 + 0) * 32 + j0);
  float4* r1 = (float4*)(xrow + (i0 + 1) * 32 + j0);
  float4* r2 = (float4*)(xrow + (i0 + 2) * 32 + j0);
  float4* r3 = (float4*)(xrow + (i0 + 3) * 32 + j0);
  float4 x0 = *r0, x1 = *r1, x2 = *r2, x3 = *r3;
  x0.x += acc0.x; x0.y += acc0.y; x0.z += acc0.z; x0.w += acc0.w;
  x1.x += acc1.x; x1.y += acc1.y; x1.z += acc1.z; x1.w += acc1.w;
  x2.x += acc2.x; x2.y += acc2.y; x2.z += acc2.z; x2.w += acc2.w;
  x3.x += acc3.x; x3.y += acc3.y; x3.z += acc3.z; x3.w += acc3.w;
  *r0 = x0; *r1 = x1; *r2 = x2; *r3 = x3;
}

// ---------------------------------------------------------------------------
// T: pool(mean over j) -> @Wp+bp -> LN -> relu -> sum over i -> @Wq1+bq1 ->
//    LN -> relu -> @Wq2+bq2.  One WG per graph.
// ---------------------------------------------------------------------------
__global__ __launch_bounds__(256) void k_tail(
    const float* __restrict__ Xp,
    const float* __restrict__ Wp, const float* __restrict__ bp,
    const float* __restrict__ gp, const float* __restrict__ cp,
    const float* __restrict__ Wq1, const float* __restrict__ bq1,
    const float* __restrict__ gq1, const float* __restrict__ cq1,
    const float* __restrict__ Wq2, const float* __restrict__ bq2,
    float* __restrict__ out) {
  int g = blockIdx.x, tid = threadIdx.x;
  __shared__ float xs_s[32 * 132];
  __shared__ float y_s[32 * 132];
  __shared__ float stat_m[32], stat_r[32];
  __shared__ float hg_s[128];
  __shared__ float q_s[128];
  __shared__ float redf[128];
  const float* Xg = Xp + ((size_t)g << 17);
#pragma unroll
  for (int m = 0; m < 16; m++) {
    int rid = m * 256 + tid;
    int hh = rid >> 5, ii = rid & 31;
    const float4* src = (const float4*)(Xg + (size_t)hh * 1024 + ii * 32);
    float s = 0.f;
#pragma unroll
    for (int q = 0; q < 8; q++) { float4 v = src[q]; s += (v.x + v.y) + (v.z + v.w); }
    xs_s[ii * 132 + hh] = s * (1.f / 32.f);
  }
  __syncthreads();
  int i_ = tid >> 3, h0 = (tid & 7) * 16;
  float acc[16];
#pragma unroll
  for (int hh = 0; hh < 16; hh++) acc[hh] = bp[h0 + hh];
  for (int k = 0; k < 128; k++) {
    float a = xs_s[i_ * 132 + k];
    const float4* wr = (const float4*)(Wp + k * 128 + h0);
    float4 w0 = wr[0], w1 = wr[1], w2 = wr[2], w3 = wr[3];
    acc[0]  += a * w0.x; acc[1]  += a * w0.y; acc[2]  += a * w0.z; acc[3]  += a * w0.w;
    acc[4]  += a * w1.x; acc[5]  += a * w1.y; acc[6]  += a * w1.z; acc[7]  += a * w1.w;
    acc[8]  += a * w2.x; acc[9]  += a * w2.y; acc[10] += a * w2.z; acc[11] += a * w2.w;
    acc[12] += a * w3.x; acc[13] += a * w3.y; acc[14] += a * w3.z; acc[15] += a * w3.w;
  }
#pragma unroll
  for (int hh = 0; hh < 16; hh++) y_s[i_ * 132 + h0 + hh] = acc[hh];
  __syncthreads();
  if (tid < 32) {
    float s = 0.f;
    for (int hh = 0; hh < 128; hh++) s += y_s[tid * 132 + hh];
    float m = s * (1.f / 128.f);
    float q = 0.f;
    for (int hh = 0; hh < 128; hh++) { float d = y_s[tid * 132 + hh] - m; q += d * d; }
    stat_m[tid] = m;
    stat_r[tid] = rsqrtf(q * (1.f / 128.f) + 1e-5f);
  }
  __syncthreads();
  {
    float m = stat_m[i_], r = stat_r[i_];
#pragma unroll
    for (int hh = 0; hh < 16; hh++) {
      int hcol = h0 + hh;
      float v = (y_s[i_ * 132 + hcol] - m) * r * gp[hcol] + cp[hcol];
      y_s[i_ * 132 + hcol] = fmaxf(v, 0.f);
    }
  }
  __syncthreads();
  if (tid < 128) {
    float s = 0.f;
#pragma unroll
    for (int ii = 0; ii < 32; ii++) s += y_s[ii * 132 + tid];
    hg_s[tid] = s;
  }
  __syncthreads();
  if (tid < 128) {
    float a = bq1[tid];
    for (int k = 0; k < 128; k++) a += hg_s[k] * Wq1[k * 128 + tid];
    q_s[tid] = a;
  }
  __syncthreads();
  if (tid == 0) {
    float s = 0.f;
    for (int k = 0; k < 128; k++) s += q_s[k];
    float m = s * (1.f / 128.f);
    float q = 0.f;
    for (int k = 0; k < 128; k++) { float d = q_s[k] - m; q += d * d; }
    stat_m[0] = m;
    stat_r[0] = rsqrtf(q * (1.f / 128.f) + 1e-5f);
  }
  __syncthreads();
  if (tid < 128) {
    float v = (q_s[tid] - stat_m[0]) * stat_r[0] * gq1[tid] + cq1[tid];
    v = fmaxf(v, 0.f);
    redf[tid] = v * Wq2[tid];
  }
  __syncthreads();
  if (tid == 0) {
    float s = 0.f;
    for (int k = 0; k < 128; k++) s += redf[k];
    out[g] = s + bq2[0];
  }
}

// ---------------------------------------------------------------------------
extern "C" void kernel_launch(void* const* d_in, const int* in_sizes, int n_in,
                              void* d_out, int out_size, void* d_ws, size_t ws_size,
                              hipStream_t stream) {
  const int*   x_idx  = (const int*)d_in[0];
  const int*   ea_idx = (const int*)d_in[1];
  const int*   tf_idx = (const int*)d_in[2];
  const int*   adj    = (const int*)d_in[3];
  const float* emb_x  = (const float*)d_in[4];
  const float* emb_ea = (const float*)d_in[5];
  const float* emb_tf = (const float*)d_in[6];
  const float* W0  = (const float*)d_in[7];
  const float* b0  = (const float*)d_in[8];
  const float* W1  = (const float*)d_in[9];
  const float* b1  = (const float*)d_in[10];
  const float* Wc  = (const float*)d_in[11];
  const float* bc  = (const float*)d_in[12];
  const float* gc  = (const float*)d_in[13];
  const float* cc  = (const float*)d_in[14];
  const float* Wp  = (const float*)d_in[15];
  const float* bp  = (const float*)d_in[16];
  const float* gp  = (const float*)d_in[17];
  const float* cp  = (const float*)d_in[18];
  const float* Wq1 = (const float*)d_in[19];
  const float* bq1 = (const float*)d_in[20];
  const float* gq1 = (const float*)d_in[21];
  const float* cq1 = (const float*)d_in[22];
  const float* Wq2 = (const float*)d_in[23];
  const float* bq2 = (const float*)d_in[24];
  float* out = (float*)d_out;

  float* ws  = (float*)d_ws;
  float* Xp  = ws;                                  // 16,777,216 floats (64 MB)
  float* tXp = ws + (size_t)16777216;               // 16,777,216 floats (64 MB)
  float* P0  = ws + (size_t)33554432;               // 4096 floats
  float* P1  = P0 + 4096;                           // 4096 floats

  k_emb_mm<<<2, 256, 0, stream>>>(emb_x, W0, b0, P0, W1, b1, P1);
  k_buildX<<<G, 256, 0, stream>>>(x_idx, tf_idx, P0, P1, emb_tf, Xp);
  for (int l = 0; l < L; l++) {
    k_conv_mlp<<<G * 8, 256, 0, stream>>>(Xp, Wc + (size_t)l * H * H,
                                          bc + l * H, gc + l * H, cc + l * H, tXp);
    k_conv_msg<<<G * 32, 256, 0, stream>>>(tXp, ea_idx, adj, emb_ea, Xp);
  }
  k_tail<<<G, 256, 0, stream>>>(Xp, Wp, bp, gp, cp, Wq1, bq1, gq1, cq1, Wq2, bq2, out);
}